// Round 2
// 1140.941 us; speedup vs baseline: 1.0567x; 1.0567x over previous
//
#include <hip/hip_runtime.h>
#include <hip/hip_fp16.h>
#include <math.h>

// Problem constants (from reference): N=100000, E=1600000, F_IN=8, H=128,
// L=4, E_FEAT=16, G=256, OUT=256. N/E derived from in_sizes at launch.
#define GG 256

typedef __attribute__((ext_vector_type(8))) short short8;
typedef __attribute__((ext_vector_type(4))) float f32x4;
typedef _Float16 half2v __attribute__((ext_vector_type(2)));

__device__ __forceinline__ unsigned short f2bf(float x) {
  union { float f; unsigned u; } v; v.f = x;
  unsigned r = v.u + 0x7fff + ((v.u >> 16) & 1);   // round-to-nearest-even
  return (unsigned short)(r >> 16);
}

__device__ __forceinline__ unsigned pack_h2(float a, float b) {
  __half2 h = __floats2half2_rn(a, b);
  return *(unsigned*)&h;
}

// v_dot2_f32_f16: D = a.lo*b.lo + a.hi*b.hi + c  (f32 accumulate)
__device__ __forceinline__ float fdot2u(unsigned a, unsigned b, float c) {
  half2v av, bv;
  __builtin_memcpy(&av, &a, 4);
  __builtin_memcpy(&bv, &b, 4);
  return __builtin_amdgcn_fdot2(av, bv, c, false);
}

// ---------- h = x @ emb_W + emb_b  ([N,8]@[8,128]); also writes bf16 shadow ----------
__global__ __launch_bounds__(256) void k_emb(const float* __restrict__ x,
    const float* __restrict__ W, const float* __restrict__ b,
    float* __restrict__ h, unsigned short* __restrict__ hb, int N) {
  int idx = blockIdx.x * 256 + threadIdx.x;      // one float4 of output per thread
  if (idx >= N * 32) return;
  int n = idx >> 5, q = idx & 31;
  const float* xr = x + (size_t)n * 8;
  float xs[8];
#pragma unroll
  for (int k = 0; k < 8; ++k) xs[k] = xr[k];
  float4 acc = ((const float4*)b)[q];
#pragma unroll
  for (int k = 0; k < 8; ++k) {
    float4 w = ((const float4*)(W + (size_t)k * 128))[q];
    acc.x += xs[k] * w.x; acc.y += xs[k] * w.y;
    acc.z += xs[k] * w.z; acc.w += xs[k] * w.w;
  }
  ((float4*)h)[idx] = acc;
  ushort4 hv4 = make_ushort4(f2bf(acc.x), f2bf(acc.y), f2bf(acc.z), f2bf(acc.w));
  *(ushort4*)(hb + (size_t)idx * 4) = hv4;
}

// ---------- edge weights -> packed fp16 PAIRS along k (dot2 layout) ----------
// eWp[l][k][c] = half2( W[l][2k][c], W[l][2k+1][c] ),  k=0..7, c=0..127
__global__ __launch_bounds__(256) void k_wconv(const float* __restrict__ eW,
    unsigned* __restrict__ eWp) {              // 4*8*128 = 4096 pairs
  int i = blockIdx.x * 256 + threadIdx.x;
  if (i >= 4096) return;
  int c = i & 127, k = (i >> 7) & 7, l = i >> 10;
  const float* base = eW + ((size_t)(l * 16 + 2 * k) * 128 + c);
  eWp[i] = pack_h2(base[0], base[128]);
}

// ---------- transpose nn_W to bf16: WT[l][n][k] = bf16(nn_W[l][k][n]) ----------
__global__ __launch_bounds__(256) void k_nnconv(const float* __restrict__ W,
    unsigned short* __restrict__ WT) {
  int i = blockIdx.x * 256 + threadIdx.x;    // i = ((l*128)+k)*128 + n
  if (i >= 4 * 128 * 128) return;
  int n = i & 127, k = (i >> 7) & 127, l = i >> 14;
  WT[((size_t)(l * 128 + n)) * 128 + k] = f2bf(W[i]);
}

// ---------- CSR build ----------
__global__ void k_hist(const int* __restrict__ dst, int* __restrict__ deg, int E) {
  int e = blockIdx.x * blockDim.x + threadIdx.x;
  if (e < E) atomicAdd(&deg[dst[e]], 1);
}

__global__ __launch_bounds__(256) void k_scan_reduce(const int* __restrict__ deg,
    int* __restrict__ bsum, int N) {
  __shared__ int sd[256];
  int i = blockIdx.x * 256 + threadIdx.x;
  sd[threadIdx.x] = (i < N) ? deg[i] : 0;
  __syncthreads();
  for (int s = 128; s > 0; s >>= 1) {
    if (threadIdx.x < s) sd[threadIdx.x] += sd[threadIdx.x + s];
    __syncthreads();
  }
  if (threadIdx.x == 0) bsum[blockIdx.x] = sd[0];
}

// single-block exclusive scan over nb (<=512) block sums
__global__ __launch_bounds__(512) void k_scan_mid(int* bsum, int nb) {
  __shared__ int sd[512];
  int t = threadIdx.x;
  int v = (t < nb) ? bsum[t] : 0;
  sd[t] = v; __syncthreads();
  for (int d = 1; d < 512; d <<= 1) {
    int xv = (t >= d) ? sd[t - d] : 0;
    __syncthreads();
    sd[t] += xv;
    __syncthreads();
  }
  if (t < nb) bsum[t] = sd[t] - v;   // exclusive
}

__global__ __launch_bounds__(256) void k_scan_final(const int* __restrict__ deg,
    const int* __restrict__ bsum, int* __restrict__ offs,
    int* __restrict__ cursor, int N) {
  __shared__ int sd[256];
  int t = threadIdx.x;
  int i = blockIdx.x * 256 + t;
  int v = (i < N) ? deg[i] : 0;
  sd[t] = v; __syncthreads();
  for (int d = 1; d < 256; d <<= 1) {           // Hillis-Steele inclusive scan
    int xv = (t >= d) ? sd[t - d] : 0;
    __syncthreads();
    sd[t] += xv;
    __syncthreads();
  }
  int off = bsum[blockIdx.x] + sd[t] - v;       // exclusive
  if (i < N) {
    offs[i] = off; cursor[i] = off;
    if (i == N - 1) offs[N] = off + v;
  }
}

// fill CSR: permute src + attr (converted to fp16, 32 B/edge) into dst order
__global__ void k_fill(const int* __restrict__ src, const int* __restrict__ dst,
    const float* __restrict__ attr, int* __restrict__ cursor,
    int* __restrict__ csrc, uint4* __restrict__ cattr16, int E) {
  int e = blockIdx.x * blockDim.x + threadIdx.x;
  if (e >= E) return;
  int d = dst[e];
  int pos = atomicAdd(&cursor[d], 1);
  csrc[pos] = src[e];
  const float4* a = (const float4*)(attr + (size_t)e * 16);
  float4 a0 = a[0], a1 = a[1], a2 = a[2], a3 = a[3];
  uint4 o0, o1;
  o0.x = pack_h2(a0.x, a0.y); o0.y = pack_h2(a0.z, a0.w);
  o0.z = pack_h2(a1.x, a1.y); o0.w = pack_h2(a1.z, a1.w);
  o1.x = pack_h2(a2.x, a2.y); o1.y = pack_h2(a2.z, a2.w);
  o1.z = pack_h2(a3.x, a3.y); o1.w = pack_h2(a3.z, a3.w);
  cattr16[(size_t)pos * 2] = o0;
  cattr16[(size_t)pos * 2 + 1] = o1;
}

// ---------- graph boundaries (batch is sorted) ----------
__global__ void k_gstart(const int* __restrict__ batch, int* __restrict__ gstart,
                         int N, int Gn) {
  int i = blockIdx.x * blockDim.x + threadIdx.x;
  if (i >= N) return;
  int b = batch[i];
  if (i == 0) { for (int g = 0; g <= b; ++g) gstart[g] = 0; }
  else { int bp = batch[i - 1]; for (int g = bp + 1; g <= b; ++g) gstart[g] = i; }
  if (i == N - 1) { for (int g = b + 1; g <= Gn; ++g) gstart[g] = N; }
}

// ---------- fused edge embed + gather + relu + aggregate (v2: fdot2) ----------
// hpa16[n] = bf16( h[n] + sum_j relu( attr[j]@edge_W + edge_b + h[src[j]] ) )
// One wave per node batch (wave-stride over nodes). Lane owns cols 2l,2l+1.
// MLP = 16x v_dot2_f32_f16 per edge, f32 accumulate seeded with bias.
// 8-deep explicit gather prefetch per edge group.
__global__ __launch_bounds__(256) void k_edge_agg(const float* __restrict__ h,
    const unsigned* __restrict__ hb32,       // bf16 shadow viewed as uint
    const uint4* __restrict__ cattr16, const int* __restrict__ csrc,
    const int* __restrict__ offs, const unsigned* __restrict__ eWp,
    const float* __restrict__ eb, unsigned* __restrict__ hpa16,
    float* __restrict__ cstats, int N) {
  int t = threadIdx.x;
  if (blockIdx.x == 0) cstats[t] = 0.f;    // 256 floats: colsum|colsumsq
  int l = t & 63;                           // lane -> columns 2l, 2l+1
  int wid = blockIdx.x * 4 + (t >> 6);
  int nw = gridDim.x * 4;
  uint2 wp[8];                              // wp[k].x pairs for col 2l, .y for 2l+1
#pragma unroll
  for (int k = 0; k < 8; ++k) wp[k] = *(const uint2*)&eWp[k * 128 + 2 * l];
  float2 bias = *(const float2*)(eb + 2 * l);
  const unsigned* hb_l = hb32 + l;          // + s*64 per edge (row = 64 uints)

#define EDGE2(JJ, UU, AX, AY)                                               \
  {                                                                         \
    uint4 q0 = cattr16[(size_t)(JJ) * 2];                                   \
    uint4 q1 = cattr16[(size_t)(JJ) * 2 + 1];                               \
    float e0 = bias.x, e1 = bias.y;                                         \
    e0 = fdot2u(q0.x, wp[0].x, e0); e1 = fdot2u(q0.x, wp[0].y, e1);         \
    e0 = fdot2u(q0.y, wp[1].x, e0); e1 = fdot2u(q0.y, wp[1].y, e1);         \
    e0 = fdot2u(q0.z, wp[2].x, e0); e1 = fdot2u(q0.z, wp[2].y, e1);         \
    e0 = fdot2u(q0.w, wp[3].x, e0); e1 = fdot2u(q0.w, wp[3].y, e1);         \
    e0 = fdot2u(q1.x, wp[4].x, e0); e1 = fdot2u(q1.x, wp[4].y, e1);         \
    e0 = fdot2u(q1.y, wp[5].x, e0); e1 = fdot2u(q1.y, wp[5].y, e1);         \
    e0 = fdot2u(q1.z, wp[6].x, e0); e1 = fdot2u(q1.z, wp[6].y, e1);         \
    e0 = fdot2u(q1.w, wp[7].x, e0); e1 = fdot2u(q1.w, wp[7].y, e1);         \
    union { unsigned uu; float ff; } c0, c1;                                \
    c0.uu = (UU) << 16; c1.uu = (UU) & 0xffff0000u;                         \
    AX += fmaxf(e0 + c0.ff, 0.f);                                           \
    AY += fmaxf(e1 + c1.ff, 0.f);                                           \
  }

  for (int n = wid; n < N; n += nw) {
    int jb = offs[n], je = offs[n + 1];
    jb = __builtin_amdgcn_readfirstlane(jb);
    je = __builtin_amdgcn_readfirstlane(je);
    float ax = 0.f, ay = 0.f, bx = 0.f, by = 0.f;
    int j = jb;
    for (; j + 8 <= je; j += 8) {
      int s0 = csrc[j + 0], s1 = csrc[j + 1], s2 = csrc[j + 2], s3 = csrc[j + 3];
      int s4 = csrc[j + 4], s5 = csrc[j + 5], s6 = csrc[j + 6], s7 = csrc[j + 7];
      unsigned u0 = hb_l[(size_t)s0 * 64], u1 = hb_l[(size_t)s1 * 64];
      unsigned u2 = hb_l[(size_t)s2 * 64], u3 = hb_l[(size_t)s3 * 64];
      unsigned u4 = hb_l[(size_t)s4 * 64], u5 = hb_l[(size_t)s5 * 64];
      unsigned u6 = hb_l[(size_t)s6 * 64], u7 = hb_l[(size_t)s7 * 64];
      EDGE2(j + 0, u0, ax, ay) EDGE2(j + 1, u1, bx, by)
      EDGE2(j + 2, u2, ax, ay) EDGE2(j + 3, u3, bx, by)
      EDGE2(j + 4, u4, ax, ay) EDGE2(j + 5, u5, bx, by)
      EDGE2(j + 6, u6, ax, ay) EDGE2(j + 7, u7, bx, by)
    }
    if (j + 4 <= je) {
      int s0 = csrc[j + 0], s1 = csrc[j + 1], s2 = csrc[j + 2], s3 = csrc[j + 3];
      unsigned u0 = hb_l[(size_t)s0 * 64], u1 = hb_l[(size_t)s1 * 64];
      unsigned u2 = hb_l[(size_t)s2 * 64], u3 = hb_l[(size_t)s3 * 64];
      EDGE2(j + 0, u0, ax, ay) EDGE2(j + 1, u1, bx, by)
      EDGE2(j + 2, u2, ax, ay) EDGE2(j + 3, u3, bx, by)
      j += 4;
    }
    for (; j < je; ++j) {
      int s0 = csrc[j];
      unsigned u0 = hb_l[(size_t)s0 * 64];
      EDGE2(j, u0, ax, ay)
    }
    float2 hvv = *(const float2*)(h + (size_t)n * 128 + 2 * l);
    float rx = hvv.x + ax + bx;
    float ry = hvv.y + ay + by;
    hpa16[(size_t)n * 64 + l] = ((unsigned)f2bf(ry) << 16) | (unsigned)f2bf(rx);
  }
#undef EDGE2
}

// ---------- MFMA node GEMM: hc = bf16(hpa) @ nn_W + nn_b, + fused BN stats ----------
// 128 rows/block, 4 waves x (2 row-tiles x 8 col-tiles) of 16x16x32 bf16 MFMA.
// A and WT (pre-transposed W, [n][k]) staged in LDS, rows padded +8 shorts
// (272 B stride -> 2-way bank aliasing, free). Stats: shfl-xor quad reduce ->
// LDS -> 256 atomics per block.
__global__ __launch_bounds__(256) void k_gemm_mfma(
    const unsigned short* __restrict__ A16, const unsigned short* __restrict__ WT16,
    const float* __restrict__ bias, float* __restrict__ hc,
    float* __restrict__ cstats, int N) {
  __shared__ short a_lds[128 * 136];
  __shared__ short w_lds[128 * 136];
  int t = threadIdx.x;
  int rowbase = blockIdx.x * 128;
  {
    int r = t >> 1;
    int off = (t & 1) * 64;              // shorts
    const short* ga = (const short*)A16 + (size_t)(rowbase + r) * 128 + off;
    short* la = &a_lds[r * 136 + off];
    const short* gw = (const short*)WT16 + (size_t)r * 128 + off;
    short* lw = &w_lds[r * 136 + off];
    if (rowbase + r < N) {
#pragma unroll
      for (int jj = 0; jj < 8; ++jj)
        *(uint4*)(la + jj * 8) = *(const uint4*)(ga + jj * 8);
    } else {
#pragma unroll
      for (int jj = 0; jj < 8; ++jj)
        *(uint4*)(la + jj * 8) = make_uint4(0, 0, 0, 0);
    }
#pragma unroll
    for (int jj = 0; jj < 8; ++jj)
      *(uint4*)(lw + jj * 8) = *(const uint4*)(gw + jj * 8);
  }
  __syncthreads();
  int w = t >> 6;
  int lane = t & 63;
  int l15 = lane & 15, quad = lane >> 4;
  f32x4 acc[2][8];
#pragma unroll
  for (int rt = 0; rt < 2; ++rt)
#pragma unroll
    for (int nt = 0; nt < 8; ++nt)
      acc[rt][nt] = (f32x4){0.f, 0.f, 0.f, 0.f};
#pragma unroll
  for (int kc = 0; kc < 4; ++kc) {
    int k0 = kc * 32 + quad * 8;
    short8 af0 = *(const short8*)&a_lds[(w * 32 + l15) * 136 + k0];
    short8 af1 = *(const short8*)&a_lds[(w * 32 + 16 + l15) * 136 + k0];
#pragma unroll
    for (int nt = 0; nt < 8; ++nt) {
      short8 bf = *(const short8*)&w_lds[(nt * 16 + l15) * 136 + k0];
      acc[0][nt] = __builtin_amdgcn_mfma_f32_16x16x32_bf16(af0, bf, acc[0][nt], 0, 0, 0);
      acc[1][nt] = __builtin_amdgcn_mfma_f32_16x16x32_bf16(af1, bf, acc[1][nt], 0, 0, 0);
    }
  }
  float sA[8], sQ[8];
#pragma unroll
  for (int nt = 0; nt < 8; ++nt) { sA[nt] = 0.f; sQ[nt] = 0.f; }
#pragma unroll
  for (int nt = 0; nt < 8; ++nt) {
    int col = nt * 16 + l15;
    float bv = bias[col];
#pragma unroll
    for (int rt = 0; rt < 2; ++rt) {
      int rbase = rowbase + w * 32 + rt * 16 + quad * 4;
#pragma unroll
      for (int reg = 0; reg < 4; ++reg) {
        int row = rbase + reg;
        float v = acc[rt][nt][reg] + bv;
        if (row < N) {
          hc[(size_t)row * 128 + col] = v;
          sA[nt] += v; sQ[nt] += v * v;
        }
      }
    }
  }
#pragma unroll
  for (int nt = 0; nt < 8; ++nt) {
    sA[nt] += __shfl_xor(sA[nt], 16);
    sA[nt] += __shfl_xor(sA[nt], 32);
    sQ[nt] += __shfl_xor(sQ[nt], 16);
    sQ[nt] += __shfl_xor(sQ[nt], 32);
  }
  __syncthreads();                    // done with a_lds/w_lds contents
  float* sdA = (float*)a_lds;         // [4][128]
  float* sdQ = (float*)w_lds;
  if (quad == 0) {
#pragma unroll
    for (int nt = 0; nt < 8; ++nt) {
      sdA[w * 128 + nt * 16 + l15] = sA[nt];
      sdQ[w * 128 + nt * 16 + l15] = sQ[nt];
    }
  }
  __syncthreads();
  if (t < 128) {
    float s = sdA[t] + sdA[128 + t] + sdA[256 + t] + sdA[384 + t];
    float s2 = sdQ[t] + sdQ[128 + t] + sdQ[256 + t] + sdQ[384 + t];
    atomicAdd(&cstats[t], s);
    atomicAdd(&cstats[128 + t], s2);
  }
}

// ---------- BN apply + exact GELU + residual: h += gelu(bn(hc)); bf16 shadow ----------
__global__ __launch_bounds__(256) void k_bn(const float* __restrict__ hc,
    const float* __restrict__ cstats,
    const float* __restrict__ g, const float* __restrict__ bb,
    float* __restrict__ h, unsigned short* __restrict__ hb, int N) {
  int idx = blockIdx.x * 256 + threadIdx.x;
  if (idx >= N * 32) return;
  int q = idx & 31;
  float invN = 1.f / (float)N;
  float4 cs = ((const float4*)cstats)[q];
  float4 cq = ((const float4*)cstats)[q + 32];
  float4 gv = ((const float4*)g)[q];
  float4 bv = ((const float4*)bb)[q];
  float4 v = ((const float4*)hc)[idx];
  float4 hv = ((const float4*)h)[idx];
#define BN1(X)                                                      \
  { float mu = cs.X * invN;                                         \
    float var = cq.X * invN - mu * mu;                              \
    float xn = (v.X - mu) * rsqrtf(var + 1e-5f) * gv.X + bv.X;      \
    hv.X += 0.5f * xn * (1.f + erff(xn * 0.70710678118654752f)); }
  BN1(x) BN1(y) BN1(z) BN1(w)
#undef BN1
  ((float4*)h)[idx] = hv;
  if (hb) {
    ushort4 hv4 = make_ushort4(f2bf(hv.x), f2bf(hv.y), f2bf(hv.z), f2bf(hv.w));
    *(ushort4*)(hb + (size_t)idx * 4) = hv4;
  }
}

// ---------- rep[g] = (sum over nodes of graph g of h[n]) @ lin_W + cnt*lin_b ----------
__global__ __launch_bounds__(256) void k_poolfinal(const float* __restrict__ h,
    const int* __restrict__ gstart, const float* __restrict__ W,
    const float* __restrict__ b, float* __restrict__ out) {
  int g = blockIdx.x;
  int t = threadIdx.x, c = t & 127, half = t >> 7;
  int n0 = gstart[g], n1 = gstart[g + 1];
  float s = 0.f;
  for (int n = n0 + half; n < n1; n += 2) s += h[(size_t)n * 128 + c];
  __shared__ float ls[256];
  __shared__ float pr[128];
  ls[t] = s; __syncthreads();
  if (t < 128) pr[t] = ls[t] + ls[t + 128];
  __syncthreads();
  float cnt = (float)(n1 - n0);
  float acc = cnt * b[t];
#pragma unroll 8
  for (int k = 0; k < 128; ++k) acc += pr[k] * W[(size_t)k * 256 + t];
  out[(size_t)g * 256 + t] = acc;
}

extern "C" void kernel_launch(void* const* d_in, const int* in_sizes, int n_in,
                              void* d_out, int out_size, void* d_ws, size_t ws_size,
                              hipStream_t stream) {
  const float* x     = (const float*)d_in[0];
  const int*   eidx  = (const int*)d_in[1];
  const float* eattr = (const float*)d_in[2];
  const int*   batch = (const int*)d_in[3];
  const float* embW  = (const float*)d_in[4];
  const float* embB  = (const float*)d_in[5];
  const float* edgeW = (const float*)d_in[6];
  const float* edgeB = (const float*)d_in[7];
  const float* nnW   = (const float*)d_in[8];
  const float* nnB   = (const float*)d_in[9];
  const float* bnG   = (const float*)d_in[10];
  const float* bnB   = (const float*)d_in[11];
  const float* linW  = (const float*)d_in[12];
  const float* linB  = (const float*)d_in[13];
  float* out = (float*)d_out;

  int N = in_sizes[0] / 8;
  int E = in_sizes[1] / 2;
  const int* src = eidx;
  const int* dst = eidx + E;

  // workspace carve-up (~220 MB)
  char* wptr = (char*)d_ws;
  auto alloc = [&](size_t bytes) {
    char* p = wptr; wptr += (bytes + 255) & ~(size_t)255; return p;
  };
  float* h      = (float*)alloc((size_t)N * 128 * 4);
  float* hc     = (float*)alloc((size_t)N * 128 * 4);   // fp32 GEMM output
  unsigned short* hb = (unsigned short*)alloc((size_t)N * 128 * 2);  // bf16 h shadow
  unsigned* hpa16 = (unsigned*)alloc((size_t)N * 64 * 4);  // bf16 h+agg (GEMM input)
  uint4* cattr16 = (uint4*)alloc((size_t)E * 32);       // fp16 attrs, 32 B/edge
  int*   csrc   = (int*)alloc((size_t)E * 4);
  int*   offs   = (int*)alloc((size_t)(N + 1) * 4);
  int*   cursor = (int*)alloc((size_t)N * 4);
  int*   deg    = (int*)alloc((size_t)N * 4);
  int nb = (N + 255) / 256;
  int*   bsum   = (int*)alloc((size_t)nb * 4);
  float* cstats = (float*)alloc(256 * 4);               // colsum | colsumsq
  unsigned* eW16 = (unsigned*)alloc(4096 * 4);          // [4][8][128] packed half2 pairs
  unsigned short* WT16 = (unsigned short*)alloc(4 * 128 * 128 * 2);  // bf16 W^T
  int*   gstart = (int*)alloc((size_t)(GG + 1) * 4);

  int q32 = (N * 32 + 255) / 256;

  hipMemsetAsync(deg, 0, (size_t)N * 4, stream);
  k_emb<<<q32, 256, 0, stream>>>(x, embW, embB, h, hb, N);
  k_wconv<<<16, 256, 0, stream>>>(edgeW, eW16);
  k_nnconv<<<256, 256, 0, stream>>>(nnW, WT16);
  k_hist<<<(E + 255) / 256, 256, 0, stream>>>(dst, deg, E);
  k_scan_reduce<<<nb, 256, 0, stream>>>(deg, bsum, N);
  k_scan_mid<<<1, 512, 0, stream>>>(bsum, nb);
  k_scan_final<<<nb, 256, 0, stream>>>(deg, bsum, offs, cursor, N);
  k_fill<<<(E + 255) / 256, 256, 0, stream>>>(src, dst, eattr, cursor, csrc, cattr16, E);
  k_gstart<<<(N + 255) / 256, 256, 0, stream>>>(batch, gstart, N, GG);

  int gblk = (N + 127) / 128;
  for (int l = 0; l < 4; ++l) {
    k_edge_agg<<<2048, 256, 0, stream>>>(h, (const unsigned*)hb, cattr16, csrc,
        offs, eW16 + (size_t)l * 1024, edgeB + (size_t)l * 128, hpa16, cstats, N);
    k_gemm_mfma<<<gblk, 256, 0, stream>>>((const unsigned short*)hpa16,
        WT16 + (size_t)l * 128 * 128, nnB + (size_t)l * 128, hc, cstats, N);
    k_bn<<<q32, 256, 0, stream>>>(hc, cstats,
        bnG + (size_t)l * 128, bnB + (size_t)l * 128, h, (l == 3) ? nullptr : hb, N);
  }
  k_poolfinal<<<GG, 256, 0, stream>>>(h, gstart, linW, linB, out);
}

// Round 3
// 1045.052 us; speedup vs baseline: 1.1536x; 1.0918x over previous
//
#include <hip/hip_runtime.h>
#include <hip/hip_fp16.h>
#include <math.h>

// Problem constants (from reference): N=100000, E=1600000, F_IN=8, H=128,
// L=4, E_FEAT=16, G=256, OUT=256. N/E derived from in_sizes at launch.
#define GG 256

typedef __attribute__((ext_vector_type(8))) short short8;
typedef __attribute__((ext_vector_type(4))) float f32x4;
typedef _Float16 half2v __attribute__((ext_vector_type(2)));
typedef __attribute__((ext_vector_type(4))) unsigned uint4v;
typedef __attribute__((ext_vector_type(8))) unsigned uint8v;

__device__ __forceinline__ unsigned short f2bf(float x) {
  union { float f; unsigned u; } v; v.f = x;
  unsigned r = v.u + 0x7fff + ((v.u >> 16) & 1);   // round-to-nearest-even
  return (unsigned short)(r >> 16);
}

__device__ __forceinline__ unsigned pack_h2(float a, float b) {
  __half2 h = __floats2half2_rn(a, b);
  return *(unsigned*)&h;
}

// v_dot2_f32_f16: D = a.lo*b.lo + a.hi*b.hi + c  (f32 accumulate)
__device__ __forceinline__ float fdot2u(unsigned a, unsigned b, float c) {
  half2v av, bv;
  __builtin_memcpy(&av, &a, 4);
  __builtin_memcpy(&bv, &b, 4);
  return __builtin_amdgcn_fdot2(av, bv, c, false);
}

// scalar loads (wave-uniform addresses) — SMEM path, SALU addressing
__device__ __forceinline__ uint4v sload4(const void* p) {
  uint4v r;
  asm volatile("s_load_dwordx4 %0, %1, 0x0"
               : "=s"(r) : "s"((unsigned long long)p));
  return r;
}
__device__ __forceinline__ uint8v sload8(const void* p) {
  uint8v r;
  asm volatile("s_load_dwordx8 %0, %1, 0x0"
               : "=s"(r) : "s"((unsigned long long)p));
  return r;
}
__device__ __forceinline__ void swait() {
  asm volatile("s_waitcnt lgkmcnt(0)" ::: "memory");
  __builtin_amdgcn_sched_barrier(0);   // rule #18: pin consumers after the wait
}

// ---------- h = x @ emb_W + emb_b  ([N,8]@[8,128]); also writes bf16 shadow ----------
__global__ __launch_bounds__(256) void k_emb(const float* __restrict__ x,
    const float* __restrict__ W, const float* __restrict__ b,
    float* __restrict__ h, unsigned short* __restrict__ hb, int N) {
  int idx = blockIdx.x * 256 + threadIdx.x;      // one float4 of output per thread
  if (idx >= N * 32) return;
  int n = idx >> 5, q = idx & 31;
  const float* xr = x + (size_t)n * 8;
  float xs[8];
#pragma unroll
  for (int k = 0; k < 8; ++k) xs[k] = xr[k];
  float4 acc = ((const float4*)b)[q];
#pragma unroll
  for (int k = 0; k < 8; ++k) {
    float4 w = ((const float4*)(W + (size_t)k * 128))[q];
    acc.x += xs[k] * w.x; acc.y += xs[k] * w.y;
    acc.z += xs[k] * w.z; acc.w += xs[k] * w.w;
  }
  ((float4*)h)[idx] = acc;
  ushort4 hv4 = make_ushort4(f2bf(acc.x), f2bf(acc.y), f2bf(acc.z), f2bf(acc.w));
  *(ushort4*)(hb + (size_t)idx * 4) = hv4;
}

// ---------- edge weights -> packed fp16 PAIRS along k (dot2 layout) ----------
// eWp[l][k][c] = half2( W[l][2k][c], W[l][2k+1][c] ),  k=0..7, c=0..127
__global__ __launch_bounds__(256) void k_wconv(const float* __restrict__ eW,
    unsigned* __restrict__ eWp) {              // 4*8*128 = 4096 pairs
  int i = blockIdx.x * 256 + threadIdx.x;
  if (i >= 4096) return;
  int c = i & 127, k = (i >> 7) & 7, l = i >> 10;
  const float* base = eW + ((size_t)(l * 16 + 2 * k) * 128 + c);
  eWp[i] = pack_h2(base[0], base[128]);
}

// ---------- transpose nn_W to bf16: WT[l][n][k] = bf16(nn_W[l][k][n]) ----------
__global__ __launch_bounds__(256) void k_nnconv(const float* __restrict__ W,
    unsigned short* __restrict__ WT) {
  int i = blockIdx.x * 256 + threadIdx.x;    // i = ((l*128)+k)*128 + n
  if (i >= 4 * 128 * 128) return;
  int n = i & 127, k = (i >> 7) & 127, l = i >> 14;
  WT[((size_t)(l * 128 + n)) * 128 + k] = f2bf(W[i]);
}

// ---------- CSR build ----------
__global__ void k_hist(const int* __restrict__ dst, int* __restrict__ deg, int E) {
  int e = blockIdx.x * blockDim.x + threadIdx.x;
  if (e < E) atomicAdd(&deg[dst[e]], 1);
}

__global__ __launch_bounds__(256) void k_scan_reduce(const int* __restrict__ deg,
    int* __restrict__ bsum, int N) {
  __shared__ int sd[256];
  int i = blockIdx.x * 256 + threadIdx.x;
  sd[threadIdx.x] = (i < N) ? deg[i] : 0;
  __syncthreads();
  for (int s = 128; s > 0; s >>= 1) {
    if (threadIdx.x < s) sd[threadIdx.x] += sd[threadIdx.x + s];
    __syncthreads();
  }
  if (threadIdx.x == 0) bsum[blockIdx.x] = sd[0];
}

// single-block exclusive scan over nb (<=512) block sums
__global__ __launch_bounds__(512) void k_scan_mid(int* bsum, int nb) {
  __shared__ int sd[512];
  int t = threadIdx.x;
  int v = (t < nb) ? bsum[t] : 0;
  sd[t] = v; __syncthreads();
  for (int d = 1; d < 512; d <<= 1) {
    int xv = (t >= d) ? sd[t - d] : 0;
    __syncthreads();
    sd[t] += xv;
    __syncthreads();
  }
  if (t < nb) bsum[t] = sd[t] - v;   // exclusive
}

__global__ __launch_bounds__(256) void k_scan_final(const int* __restrict__ deg,
    const int* __restrict__ bsum, int* __restrict__ offs,
    int* __restrict__ cursor, int N) {
  __shared__ int sd[256];
  int t = threadIdx.x;
  int i = blockIdx.x * 256 + t;
  int v = (i < N) ? deg[i] : 0;
  sd[t] = v; __syncthreads();
  for (int d = 1; d < 256; d <<= 1) {           // Hillis-Steele inclusive scan
    int xv = (t >= d) ? sd[t - d] : 0;
    __syncthreads();
    sd[t] += xv;
    __syncthreads();
  }
  int off = bsum[blockIdx.x] + sd[t] - v;       // exclusive
  if (i < N) {
    offs[i] = off; cursor[i] = off;
    if (i == N - 1) offs[N] = off + v;
  }
}

// fill CSR: permute src + attr (converted to fp16, 32 B/edge) into dst order
__global__ void k_fill(const int* __restrict__ src, const int* __restrict__ dst,
    const float* __restrict__ attr, int* __restrict__ cursor,
    int* __restrict__ csrc, uint4* __restrict__ cattr16, int E) {
  int e = blockIdx.x * blockDim.x + threadIdx.x;
  if (e >= E) return;
  int d = dst[e];
  int pos = atomicAdd(&cursor[d], 1);
  csrc[pos] = src[e];
  const float4* a = (const float4*)(attr + (size_t)e * 16);
  float4 a0 = a[0], a1 = a[1], a2 = a[2], a3 = a[3];
  uint4 o0, o1;
  o0.x = pack_h2(a0.x, a0.y); o0.y = pack_h2(a0.z, a0.w);
  o0.z = pack_h2(a1.x, a1.y); o0.w = pack_h2(a1.z, a1.w);
  o1.x = pack_h2(a2.x, a2.y); o1.y = pack_h2(a2.z, a2.w);
  o1.z = pack_h2(a3.x, a3.y); o1.w = pack_h2(a3.z, a3.w);
  cattr16[(size_t)pos * 2] = o0;
  cattr16[(size_t)pos * 2 + 1] = o1;
}

// ---------- graph boundaries (batch is sorted) ----------
__global__ void k_gstart(const int* __restrict__ batch, int* __restrict__ gstart,
                         int N, int Gn) {
  int i = blockIdx.x * blockDim.x + threadIdx.x;
  if (i >= N) return;
  int b = batch[i];
  if (i == 0) { for (int g = 0; g <= b; ++g) gstart[g] = 0; }
  else { int bp = batch[i - 1]; for (int g = bp + 1; g <= b; ++g) gstart[g] = i; }
  if (i == N - 1) { for (int g = b + 1; g <= Gn; ++g) gstart[g] = N; }
}

// ---------- fused edge embed + gather + relu + aggregate (v3: SMEM scalar path) ----------
// hpa16[n] = bf16( h[n] + sum_j relu( attr[j]@edge_W + edge_b + h[src[j]] ) )
// Wave-stride over nodes. Lane owns cols 2l,2l+1.
// Per 4-edge group: s_load_dwordx4 (csrc) + 4x s_load_dwordx8 (attrs) -> SGPRs,
// gathers are SGPR-base + invariant VGPR lane offset (zero per-edge VALU addr).
// MLP = 16x v_dot2_f32_f16 per edge with SGPR src0, f32 accumulate from bias.
__global__ __launch_bounds__(256) void k_edge_agg(const float* __restrict__ h,
    const unsigned* __restrict__ hb32,       // bf16 shadow viewed as uint
    const uint4* __restrict__ cattr16, const int* __restrict__ csrc,
    const int* __restrict__ offs, const unsigned* __restrict__ eWp,
    const float* __restrict__ eb, unsigned* __restrict__ hpa16,
    float* __restrict__ cstats, int N) {
  int t = threadIdx.x;
  if (blockIdx.x == 0) cstats[t] = 0.f;    // 256 floats: colsum|colsumsq
  int l = t & 63;                           // lane -> columns 2l, 2l+1
  int wid = blockIdx.x * 4 + (t >> 6);
  int nw = gridDim.x * 4;
  uint2 wp[8];                              // wp[k].x pairs for col 2l, .y for 2l+1
#pragma unroll
  for (int k = 0; k < 8; ++k) wp[k] = *(const uint2*)&eWp[k * 128 + 2 * l];
  float2 bias = *(const float2*)(eb + 2 * l);
  const unsigned* hb_l = hb32 + l;          // + s*64 per edge (row = 64 uints)

// attrs from SGPR vector A (8 dwords = 1 edge), gather word UU
#define EDGE_SG(A, UU, AX, AY)                                              \
  {                                                                         \
    float e0 = bias.x, e1 = bias.y;                                         \
    e0 = fdot2u(A[0], wp[0].x, e0); e1 = fdot2u(A[0], wp[0].y, e1);         \
    e0 = fdot2u(A[1], wp[1].x, e0); e1 = fdot2u(A[1], wp[1].y, e1);         \
    e0 = fdot2u(A[2], wp[2].x, e0); e1 = fdot2u(A[2], wp[2].y, e1);         \
    e0 = fdot2u(A[3], wp[3].x, e0); e1 = fdot2u(A[3], wp[3].y, e1);         \
    e0 = fdot2u(A[4], wp[4].x, e0); e1 = fdot2u(A[4], wp[4].y, e1);         \
    e0 = fdot2u(A[5], wp[5].x, e0); e1 = fdot2u(A[5], wp[5].y, e1);         \
    e0 = fdot2u(A[6], wp[6].x, e0); e1 = fdot2u(A[6], wp[6].y, e1);         \
    e0 = fdot2u(A[7], wp[7].x, e0); e1 = fdot2u(A[7], wp[7].y, e1);         \
    union { unsigned uu; float ff; } c0, c1;                                \
    c0.uu = (UU) << 16; c1.uu = (UU) & 0xffff0000u;                         \
    AX += fmaxf(e0 + c0.ff, 0.f);                                           \
    AY += fmaxf(e1 + c1.ff, 0.f);                                           \
  }

// plain-VMEM fallback for remainder edges
#define EDGE2(JJ, UU, AX, AY)                                               \
  {                                                                         \
    uint4 q0 = cattr16[(size_t)(JJ) * 2];                                   \
    uint4 q1 = cattr16[(size_t)(JJ) * 2 + 1];                               \
    float e0 = bias.x, e1 = bias.y;                                         \
    e0 = fdot2u(q0.x, wp[0].x, e0); e1 = fdot2u(q0.x, wp[0].y, e1);         \
    e0 = fdot2u(q0.y, wp[1].x, e0); e1 = fdot2u(q0.y, wp[1].y, e1);         \
    e0 = fdot2u(q0.z, wp[2].x, e0); e1 = fdot2u(q0.z, wp[2].y, e1);         \
    e0 = fdot2u(q0.w, wp[3].x, e0); e1 = fdot2u(q0.w, wp[3].y, e1);         \
    e0 = fdot2u(q1.x, wp[4].x, e0); e1 = fdot2u(q1.x, wp[4].y, e1);         \
    e0 = fdot2u(q1.y, wp[5].x, e0); e1 = fdot2u(q1.y, wp[5].y, e1);         \
    e0 = fdot2u(q1.z, wp[6].x, e0); e1 = fdot2u(q1.z, wp[6].y, e1);         \
    e0 = fdot2u(q1.w, wp[7].x, e0); e1 = fdot2u(q1.w, wp[7].y, e1);         \
    union { unsigned uu; float ff; } c0, c1;                                \
    c0.uu = (UU) << 16; c1.uu = (UU) & 0xffff0000u;                         \
    AX += fmaxf(e0 + c0.ff, 0.f);                                           \
    AY += fmaxf(e1 + c1.ff, 0.f);                                           \
  }

  for (int n = wid; n < N; n += nw) {
    int jb = offs[n], je = offs[n + 1];
    jb = __builtin_amdgcn_readfirstlane(jb);
    je = __builtin_amdgcn_readfirstlane(je);
    float ax = 0.f, ay = 0.f, bx = 0.f, by = 0.f;
    int j = jb;
    for (; j + 4 <= je; j += 4) {
      const char* ab = (const char*)cattr16 + ((unsigned long long)(unsigned)j << 5);
      uint4v sc = sload4((const char*)csrc + ((unsigned long long)(unsigned)j << 2));
      uint8v A0 = sload8(ab);
      uint8v A1 = sload8(ab + 32);
      uint8v A2 = sload8(ab + 64);
      uint8v A3 = sload8(ab + 96);
      swait();
      const unsigned* r0 = (const unsigned*)((const char*)hb32 + ((unsigned long long)sc[0] << 8));
      const unsigned* r1 = (const unsigned*)((const char*)hb32 + ((unsigned long long)sc[1] << 8));
      const unsigned* r2 = (const unsigned*)((const char*)hb32 + ((unsigned long long)sc[2] << 8));
      const unsigned* r3 = (const unsigned*)((const char*)hb32 + ((unsigned long long)sc[3] << 8));
      unsigned u0 = r0[l], u1 = r1[l], u2 = r2[l], u3 = r3[l];
      EDGE_SG(A0, u0, ax, ay)
      EDGE_SG(A1, u1, bx, by)
      EDGE_SG(A2, u2, ax, ay)
      EDGE_SG(A3, u3, bx, by)
    }
    for (; j < je; ++j) {
      int s0 = csrc[j];
      unsigned u0 = hb_l[(size_t)s0 * 64];
      EDGE2(j, u0, ax, ay)
    }
    float2 hvv = *(const float2*)(h + (size_t)n * 128 + 2 * l);
    float rx = hvv.x + ax + bx;
    float ry = hvv.y + ay + by;
    hpa16[(size_t)n * 64 + l] = ((unsigned)f2bf(ry) << 16) | (unsigned)f2bf(rx);
  }
#undef EDGE_SG
#undef EDGE2
}

// ---------- MFMA node GEMM: hc = bf16(hpa) @ nn_W + nn_b, + fused BN stats ----------
// 128 rows/block, 4 waves x (2 row-tiles x 8 col-tiles) of 16x16x32 bf16 MFMA.
// A and WT (pre-transposed W, [n][k]) staged in LDS, rows padded +8 shorts
// (272 B stride -> 2-way bank aliasing, free). Stats: shfl-xor quad reduce ->
// LDS -> 256 atomics per block.
__global__ __launch_bounds__(256) void k_gemm_mfma(
    const unsigned short* __restrict__ A16, const unsigned short* __restrict__ WT16,
    const float* __restrict__ bias, float* __restrict__ hc,
    float* __restrict__ cstats, int N) {
  __shared__ short a_lds[128 * 136];
  __shared__ short w_lds[128 * 136];
  int t = threadIdx.x;
  int rowbase = blockIdx.x * 128;
  {
    int r = t >> 1;
    int off = (t & 1) * 64;              // shorts
    const short* ga = (const short*)A16 + (size_t)(rowbase + r) * 128 + off;
    short* la = &a_lds[r * 136 + off];
    const short* gw = (const short*)WT16 + (size_t)r * 128 + off;
    short* lw = &w_lds[r * 136 + off];
    if (rowbase + r < N) {
#pragma unroll
      for (int jj = 0; jj < 8; ++jj)
        *(uint4*)(la + jj * 8) = *(const uint4*)(ga + jj * 8);
    } else {
#pragma unroll
      for (int jj = 0; jj < 8; ++jj)
        *(uint4*)(la + jj * 8) = make_uint4(0, 0, 0, 0);
    }
#pragma unroll
    for (int jj = 0; jj < 8; ++jj)
      *(uint4*)(lw + jj * 8) = *(const uint4*)(gw + jj * 8);
  }
  __syncthreads();
  int w = t >> 6;
  int lane = t & 63;
  int l15 = lane & 15, quad = lane >> 4;
  f32x4 acc[2][8];
#pragma unroll
  for (int rt = 0; rt < 2; ++rt)
#pragma unroll
    for (int nt = 0; nt < 8; ++nt)
      acc[rt][nt] = (f32x4){0.f, 0.f, 0.f, 0.f};
#pragma unroll
  for (int kc = 0; kc < 4; ++kc) {
    int k0 = kc * 32 + quad * 8;
    short8 af0 = *(const short8*)&a_lds[(w * 32 + l15) * 136 + k0];
    short8 af1 = *(const short8*)&a_lds[(w * 32 + 16 + l15) * 136 + k0];
#pragma unroll
    for (int nt = 0; nt < 8; ++nt) {
      short8 bf = *(const short8*)&w_lds[(nt * 16 + l15) * 136 + k0];
      acc[0][nt] = __builtin_amdgcn_mfma_f32_16x16x32_bf16(af0, bf, acc[0][nt], 0, 0, 0);
      acc[1][nt] = __builtin_amdgcn_mfma_f32_16x16x32_bf16(af1, bf, acc[1][nt], 0, 0, 0);
    }
  }
  float sA[8], sQ[8];
#pragma unroll
  for (int nt = 0; nt < 8; ++nt) { sA[nt] = 0.f; sQ[nt] = 0.f; }
#pragma unroll
  for (int nt = 0; nt < 8; ++nt) {
    int col = nt * 16 + l15;
    float bv = bias[col];
#pragma unroll
    for (int rt = 0; rt < 2; ++rt) {
      int rbase = rowbase + w * 32 + rt * 16 + quad * 4;
#pragma unroll
      for (int reg = 0; reg < 4; ++reg) {
        int row = rbase + reg;
        float v = acc[rt][nt][reg] + bv;
        if (row < N) {
          hc[(size_t)row * 128 + col] = v;
          sA[nt] += v; sQ[nt] += v * v;
        }
      }
    }
  }
#pragma unroll
  for (int nt = 0; nt < 8; ++nt) {
    sA[nt] += __shfl_xor(sA[nt], 16);
    sA[nt] += __shfl_xor(sA[nt], 32);
    sQ[nt] += __shfl_xor(sQ[nt], 16);
    sQ[nt] += __shfl_xor(sQ[nt], 32);
  }
  __syncthreads();                    // done with a_lds/w_lds contents
  float* sdA = (float*)a_lds;         // [4][128]
  float* sdQ = (float*)w_lds;
  if (quad == 0) {
#pragma unroll
    for (int nt = 0; nt < 8; ++nt) {
      sdA[w * 128 + nt * 16 + l15] = sA[nt];
      sdQ[w * 128 + nt * 16 + l15] = sQ[nt];
    }
  }
  __syncthreads();
  if (t < 128) {
    float s = sdA[t] + sdA[128 + t] + sdA[256 + t] + sdA[384 + t];
    float s2 = sdQ[t] + sdQ[128 + t] + sdQ[256 + t] + sdQ[384 + t];
    atomicAdd(&cstats[t], s);
    atomicAdd(&cstats[128 + t], s2);
  }
}

// ---------- BN apply + exact GELU + residual: h += gelu(bn(hc)); bf16 shadow ----------
__global__ __launch_bounds__(256) void k_bn(const float* __restrict__ hc,
    const float* __restrict__ cstats,
    const float* __restrict__ g, const float* __restrict__ bb,
    float* __restrict__ h, unsigned short* __restrict__ hb, int N) {
  int idx = blockIdx.x * 256 + threadIdx.x;
  if (idx >= N * 32) return;
  int q = idx & 31;
  float invN = 1.f / (float)N;
  float4 cs = ((const float4*)cstats)[q];
  float4 cq = ((const float4*)cstats)[q + 32];
  float4 gv = ((const float4*)g)[q];
  float4 bv = ((const float4*)bb)[q];
  float4 v = ((const float4*)hc)[idx];
  float4 hv = ((const float4*)h)[idx];
#define BN1(X)                                                      \
  { float mu = cs.X * invN;                                         \
    float var = cq.X * invN - mu * mu;                              \
    float xn = (v.X - mu) * rsqrtf(var + 1e-5f) * gv.X + bv.X;      \
    hv.X += 0.5f * xn * (1.f + erff(xn * 0.70710678118654752f)); }
  BN1(x) BN1(y) BN1(z) BN1(w)
#undef BN1
  ((float4*)h)[idx] = hv;
  if (hb) {
    ushort4 hv4 = make_ushort4(f2bf(hv.x), f2bf(hv.y), f2bf(hv.z), f2bf(hv.w));
    *(ushort4*)(hb + (size_t)idx * 4) = hv4;
  }
}

// ---------- rep[g] = (sum over nodes of graph g of h[n]) @ lin_W + cnt*lin_b ----------
__global__ __launch_bounds__(256) void k_poolfinal(const float* __restrict__ h,
    const int* __restrict__ gstart, const float* __restrict__ W,
    const float* __restrict__ b, float* __restrict__ out) {
  int g = blockIdx.x;
  int t = threadIdx.x, c = t & 127, half = t >> 7;
  int n0 = gstart[g], n1 = gstart[g + 1];
  float s = 0.f;
  for (int n = n0 + half; n < n1; n += 2) s += h[(size_t)n * 128 + c];
  __shared__ float ls[256];
  __shared__ float pr[128];
  ls[t] = s; __syncthreads();
  if (t < 128) pr[t] = ls[t] + ls[t + 128];
  __syncthreads();
  float cnt = (float)(n1 - n0);
  float acc = cnt * b[t];
#pragma unroll 8
  for (int k = 0; k < 128; ++k) acc += pr[k] * W[(size_t)k * 256 + t];
  out[(size_t)g * 256 + t] = acc;
}

extern "C" void kernel_launch(void* const* d_in, const int* in_sizes, int n_in,
                              void* d_out, int out_size, void* d_ws, size_t ws_size,
                              hipStream_t stream) {
  const float* x     = (const float*)d_in[0];
  const int*   eidx  = (const int*)d_in[1];
  const float* eattr = (const float*)d_in[2];
  const int*   batch = (const int*)d_in[3];
  const float* embW  = (const float*)d_in[4];
  const float* embB  = (const float*)d_in[5];
  const float* edgeW = (const float*)d_in[6];
  const float* edgeB = (const float*)d_in[7];
  const float* nnW   = (const float*)d_in[8];
  const float* nnB   = (const float*)d_in[9];
  const float* bnG   = (const float*)d_in[10];
  const float* bnB   = (const float*)d_in[11];
  const float* linW  = (const float*)d_in[12];
  const float* linB  = (const float*)d_in[13];
  float* out = (float*)d_out;

  int N = in_sizes[0] / 8;
  int E = in_sizes[1] / 2;
  const int* src = eidx;
  const int* dst = eidx + E;

  // workspace carve-up (~220 MB)
  char* wptr = (char*)d_ws;
  auto alloc = [&](size_t bytes) {
    char* p = wptr; wptr += (bytes + 255) & ~(size_t)255; return p;
  };
  float* h      = (float*)alloc((size_t)N * 128 * 4);
  float* hc     = (float*)alloc((size_t)N * 128 * 4);   // fp32 GEMM output
  unsigned short* hb = (unsigned short*)alloc((size_t)N * 128 * 2);  // bf16 h shadow
  unsigned* hpa16 = (unsigned*)alloc((size_t)N * 64 * 4);  // bf16 h+agg (GEMM input)
  uint4* cattr16 = (uint4*)alloc((size_t)E * 32);       // fp16 attrs, 32 B/edge
  int*   csrc   = (int*)alloc((size_t)E * 4);
  int*   offs   = (int*)alloc((size_t)(N + 1) * 4);
  int*   cursor = (int*)alloc((size_t)N * 4);
  int*   deg    = (int*)alloc((size_t)N * 4);
  int nb = (N + 255) / 256;
  int*   bsum   = (int*)alloc((size_t)nb * 4);
  float* cstats = (float*)alloc(256 * 4);               // colsum | colsumsq
  unsigned* eW16 = (unsigned*)alloc(4096 * 4);          // [4][8][128] packed half2 pairs
  unsigned short* WT16 = (unsigned short*)alloc(4 * 128 * 128 * 2);  // bf16 W^T
  int*   gstart = (int*)alloc((size_t)(GG + 1) * 4);

  int q32 = (N * 32 + 255) / 256;

  hipMemsetAsync(deg, 0, (size_t)N * 4, stream);
  k_emb<<<q32, 256, 0, stream>>>(x, embW, embB, h, hb, N);
  k_wconv<<<16, 256, 0, stream>>>(edgeW, eW16);
  k_nnconv<<<256, 256, 0, stream>>>(nnW, WT16);
  k_hist<<<(E + 255) / 256, 256, 0, stream>>>(dst, deg, E);
  k_scan_reduce<<<nb, 256, 0, stream>>>(deg, bsum, N);
  k_scan_mid<<<1, 512, 0, stream>>>(bsum, nb);
  k_scan_final<<<nb, 256, 0, stream>>>(deg, bsum, offs, cursor, N);
  k_fill<<<(E + 255) / 256, 256, 0, stream>>>(src, dst, eattr, cursor, csrc, cattr16, E);
  k_gstart<<<(N + 255) / 256, 256, 0, stream>>>(batch, gstart, N, GG);

  int gblk = (N + 127) / 128;
  for (int l = 0; l < 4; ++l) {
    k_edge_agg<<<8192, 256, 0, stream>>>(h, (const unsigned*)hb, cattr16, csrc,
        offs, eW16 + (size_t)l * 1024, edgeB + (size_t)l * 128, hpa16, cstats, N);
    k_gemm_mfma<<<gblk, 256, 0, stream>>>((const unsigned short*)hpa16,
        WT16 + (size_t)l * 128 * 128, nnB + (size_t)l * 128, hc, cstats, N);
    k_bn<<<q32, 256, 0, stream>>>(hc, cstats,
        bnG + (size_t)l * 128, bnB + (size_t)l * 128, h, (l == 3) ? nullptr : hb, N);
  }
  k_poolfinal<<<GG, 256, 0, stream>>>(h, gstart, linW, linB, out);
}